// Round 2
// 158.262 us; speedup vs baseline: 1.0117x; 1.0117x over previous
//
#include <hip/hip_runtime.h>

#define B_ 8
#define C_ 128
#define W_ 4096
#define D_ 16
// D^-0.5 * log2(e): folded into Wq/bq; exp2 domain (v_exp_f32)
#define SCALE2 0.3606737602222409f

typedef short bf16x8 __attribute__((ext_vector_type(8)));
typedef float f32x4 __attribute__((ext_vector_type(4)));
typedef float f32x16 __attribute__((ext_vector_type(16)));

__device__ __forceinline__ unsigned short f2bf(float f) {
    unsigned int u = __float_as_uint(f);
    u += 0x7fffu + ((u >> 16) & 1u);
    return (unsigned short)(u >> 16);
}
__device__ __forceinline__ float bf2f(unsigned short h) {
    return __uint_as_float(((unsigned int)h) << 16);
}
// pack two f32 -> u32 of 2 bf16 (TRUNCATED) in ONE v_perm_b32
__device__ __forceinline__ unsigned int pk2bf(float lo, float hi) {
    return __builtin_amdgcn_perm(__float_as_uint(hi), __float_as_uint(lo), 0x07060302u);
}
__device__ __forceinline__ bf16x8 u4_to_bf8(unsigned int a, unsigned int b,
                                            unsigned int c, unsigned int d) {
    union { uint4 u; bf16x8 v; } t;
    t.u = make_uint4(a, b, c, d);
    return t.v;
}
__device__ __forceinline__ bf16x8 uint4_as_bf8(uint4 u) {
    union { uint4 u; bf16x8 v; } t;
    t.u = u;
    return t.v;
}
// exp2 8 S-values (C-regs r0..r0+7) -> one K=16 fragment as uint4
__device__ __forceinline__ uint4 exp2pkq(f32x16 s, int r0) {
    return make_uint4(
        pk2bf(__builtin_amdgcn_exp2f(s[r0+0]), __builtin_amdgcn_exp2f(s[r0+1])),
        pk2bf(__builtin_amdgcn_exp2f(s[r0+2]), __builtin_amdgcn_exp2f(s[r0+3])),
        pk2bf(__builtin_amdgcn_exp2f(s[r0+4]), __builtin_amdgcn_exp2f(s[r0+5])),
        pk2bf(__builtin_amdgcn_exp2f(s[r0+6]), __builtin_amdgcn_exp2f(s[r0+7])));
}
// LDS chunk swizzle for proj staging
__device__ __forceinline__ int xswz(int j, int c8) {
    return c8 ^ (j & 7) ^ ((j >> 3) & 7);
}

// ---------------- prep: Wv -> bf16; [Wq*SCALE2 ; Wk] -> bf16 ----------------
__global__ __launch_bounds__(256) void prep(
    const float* __restrict__ Wq, const float* __restrict__ Wk, const float* __restrict__ Wv,
    unsigned short* __restrict__ Wvbf, unsigned short* __restrict__ Wqkbf)
{
    int g = blockIdx.x * 256 + threadIdx.x;
    const float* src; unsigned short* dst; float sc = 1.0f;
    if (g < 4096)      { src = Wv + g * 4;            dst = Wvbf + g * 4; }
    else if (g < 4608) { int t = g - 4096; src = Wq + t * 4; dst = Wqkbf + t * 4; sc = SCALE2; }
    else               { int t = g - 4608; src = Wk + t * 4; dst = Wqkbf + 2048 + t * 4; }
    float4 v = *(const float4*)src;
    unsigned short h[4] = {f2bf(v.x * sc), f2bf(v.y * sc), f2bf(v.z * sc), f2bf(v.w * sc)};
    *(ushort4*)dst = *(ushort4*)h;
}

// ---------------- proj: q,k,v in one pass; frag-major outputs ----------------
// qws2/kws2: [b][pos/32][h 0-1][pos%32][8 dims]  (dims h*8+i; K=16, no padding)
// vws2:      [b][jt][kf 0-1][h 0-1][c 128][8]    slot i -> j = jt*32 + kf*16+4h+(i&3)+8*(i>>2)
__global__ __launch_bounds__(256) void proj(
    const float* __restrict__ x, const unsigned short* __restrict__ Wvbf,
    const unsigned short* __restrict__ Wqkbf,
    const float* __restrict__ bqp, const float* __restrict__ bkp, const float* __restrict__ bvp,
    unsigned short* __restrict__ qws2, unsigned short* __restrict__ kws2,
    unsigned short* __restrict__ vws2)
{
    __shared__ unsigned short xbf[32 * 128];     // [j][c] swizzled chunks, 8KB
    __shared__ unsigned short outs[128 * 36];    // v bounce [c][j], 9KB
    __shared__ unsigned short qk_s[2][32][24];   // q/k bounce [qk][pos][dim], 3KB (row 48B)

    int b  = blockIdx.x & 7;
    int j0 = (blockIdx.x >> 3) * 32;
    int jt = j0 >> 5;
    int tid = threadIdx.x;
    int wid = tid >> 6, lane = tid & 63, n = lane & 15, q4 = lane >> 4;

    // stage x tile [128c][32j] -> bf16 LDS [j][c] swizzled; c-paired v_perm packs
    {
        unsigned int* xbf32 = (unsigned int*)xbf;
#pragma unroll
        for (int i = 0; i < 8; i++) {
            int p = tid + 256 * i;            // 2048 c-pair slots
            int c2 = p >> 5;                  // c = 2*c2, 2*c2+1
            int j  = p & 31;
            const float* xp = x + (size_t)(b * C_ + 2 * c2) * W_ + j0 + j;
            float lo = xp[0];
            float hi = xp[W_];
            xbf32[j * 64 + xswz(j, c2 >> 2) * 4 + (c2 & 3)] = pk2bf(lo, hi);
        }
    }
    __syncthreads();

    const f32x4 zero = {0.f, 0.f, 0.f, 0.f};
    f32x4 accv[2][2]; f32x4 accqk = zero;
#pragma unroll
    for (int os = 0; os < 2; os++)
#pragma unroll
        for (int js = 0; js < 2; js++) accv[os][js] = zero;

    int isK = wid >> 1;          // waves 0,1: q; waves 2,3: k
    int jsm = wid & 1;           // which j-tile this wave's q/k MFMA covers

#pragma unroll
    for (int kk = 0; kk < 128; kk += 32) {
        bf16x8 av[2], aqkf, bx[2];
#pragma unroll
        for (int os = 0; os < 2; os++)
            av[os] = *(const bf16x8*)(Wvbf + (wid * 32 + os * 16 + n) * 128 + kk + q4 * 8);
        aqkf = *(const bf16x8*)(Wqkbf + (isK * 16 + n) * 128 + kk + q4 * 8);
#pragma unroll
        for (int js = 0; js < 2; js++) {
            int j = js * 16 + n;
            bx[js] = *(const bf16x8*)&xbf[j * 128 + xswz(j, (kk >> 3) + q4) * 8];
        }
#pragma unroll
        for (int os = 0; os < 2; os++)
#pragma unroll
            for (int js = 0; js < 2; js++)
                accv[os][js] = __builtin_amdgcn_mfma_f32_16x16x32_bf16(av[os], bx[js], accv[os][js], 0, 0, 0);
        accqk = __builtin_amdgcn_mfma_f32_16x16x32_bf16(aqkf, bx[jsm], accqk, 0, 0, 0);
    }

    // q/k epilogue -> qk_s (C layout: row d = q4*4+r, col pos = jsm*16+n)
    {
        int pos = jsm * 16 + n;
        const float* bias = isK ? bkp : bqp;
        float bsc = isK ? 1.0f : SCALE2;
#pragma unroll
        for (int r = 0; r < 4; r++)
            qk_s[isK][pos][q4 * 4 + r] = f2bf(accqk[r] + bias[q4 * 4 + r] * bsc);
    }

    // v epilogue -> outs [c][j]
    float bvv[2][4];
#pragma unroll
    for (int os = 0; os < 2; os++)
#pragma unroll
        for (int r = 0; r < 4; r++) bvv[os][r] = bvp[wid * 32 + os * 16 + q4 * 4 + r];
#pragma unroll
    for (int os = 0; os < 2; os++)
#pragma unroll
        for (int js = 0; js < 2; js++)
#pragma unroll
            for (int r = 0; r < 4; r++) {
                int c = wid * 32 + os * 16 + q4 * 4 + r;
                int j = js * 16 + n;
                outs[c * 36 + j] = f2bf(accv[os][js][r] + bvv[os][r]);
            }
    __syncthreads();

    // qws2/kws2 writers (128 tasks x 16B)
    if (tid < 128) {
        int qk = tid >> 6, hh = (tid >> 5) & 1, jl = tid & 31;
        uint4 v = *(const uint4*)&qk_s[qk][jl][hh * 8];
        unsigned short* dst = (qk ? kws2 : qws2)
            + (size_t)(b * 128 + jt) * 512 + hh * 256 + jl * 8;
        *(uint4*)dst = v;
    }
    // vws2 writers (512 tasks x 16B): slot i -> j = kf*16+4h+{0..3,8..11}
#pragma unroll
    for (int rep = 0; rep < 2; rep++) {
        int t = tid + rep * 256;
        int c = t & 127, sel = t >> 7;          // sel = kf*2+h
        int jb = (sel >> 1) * 16 + (sel & 1) * 4;
        uint2 lo = *(const uint2*)&outs[c * 36 + jb];
        uint2 hi = *(const uint2*)&outs[c * 36 + jb + 8];
        *(uint4*)(vws2 + ((size_t)(b * 128 + jt) * 4 + sel) * 1024 + c * 8) =
            make_uint4(lo.x, lo.y, hi.x, hi.y);
    }
}

// ---------------- row_stats: partial l-sums via 32x32x16, w split 4 ways ----------------
// rlp[wsp][b][W] = sum over w-quarter of exp2(s2[j,w])
__global__ __launch_bounds__(256) void row_stats(
    const unsigned short* __restrict__ qws2, const unsigned short* __restrict__ kws2,
    float* __restrict__ rlp)
{
    int blk = blockIdx.x;                // grid 1024
    int b = blk & 7;
    int j0 = ((blk >> 3) & 31) * 128;
    int wsp = blk >> 8;                  // 0..3
    int tid = threadIdx.x;
    int wid = tid >> 6, lane = tid & 63, wl = lane & 31, h = lane >> 5;

    const unsigned short* qb = qws2 + (size_t)b * 65536;
    const unsigned short* kb = kws2 + (size_t)b * 65536;
    int jt = (j0 >> 5) + wid;

    bf16x8 aq = *(const bf16x8*)(qb + (size_t)jt * 512 + h * 256 + wl * 8);
    f32x16 zero16 = {0.f,0.f,0.f,0.f,0.f,0.f,0.f,0.f,0.f,0.f,0.f,0.f,0.f,0.f,0.f,0.f};

    float lt[16];
#pragma unroll
    for (int r = 0; r < 16; r++) lt[r] = 0.f;

    bf16x8 bkc = *(const bf16x8*)(kb + (size_t)(wsp * 32) * 512 + h * 256 + wl * 8);
    for (int t = 0; t < 32; t++) {
        f32x16 s = __builtin_amdgcn_mfma_f32_32x32x16_bf16(aq, bkc, zero16, 0, 0, 0);
        int tn = wsp * 32 + ((t + 1) & 31);   // branchless wrap prefetch
        bkc = *(const bf16x8*)(kb + (size_t)tn * 512 + h * 256 + wl * 8);
#pragma unroll
        for (int r = 0; r < 16; r++) lt[r] += __builtin_amdgcn_exp2f(s[r]);
    }
    // reduce over 32 w-lanes (same half)
#pragma unroll
    for (int mask = 1; mask < 32; mask <<= 1)
#pragma unroll
        for (int r = 0; r < 16; r++) lt[r] += __shfl_xor(lt[r], mask, 64);
    if (wl == 0) {
        // C rows: r=4g+e -> j-local = e + 8g + 4h
#pragma unroll
        for (int g = 0; g < 4; g++) {
            f32x4 v = {lt[4*g+0], lt[4*g+1], lt[4*g+2], lt[4*g+3]};
            *(f32x4*)(rlp + (size_t)wsp * 32768 + (size_t)b * W_ + j0 + wid * 32 + 4 * h + 8 * g) = v;
        }
    }
}

// ---------------- finl: rls[j] = 1 / sum of 4 partials ----------------
__global__ __launch_bounds__(256) void finl(const float* __restrict__ rlp,
                                            float* __restrict__ rls)
{
    int g = blockIdx.x * 256 + threadIdx.x;   // 32768 = B*W
    float l = rlp[g] + rlp[32768 + g] + rlp[65536 + g] + rlp[98304 + g];
    rls[g] = 1.0f / l;
}

// ---------------- vscale: v'[c,j] = v[c,j] * rls[j], in-place on vws2 ----------------
__global__ __launch_bounds__(256) void vscale(unsigned short* __restrict__ vws2,
                                              const float* __restrict__ rls)
{
    int g = blockIdx.x * 256 + threadIdx.x;   // 524288 16B-units
    int hh = (g >> 7) & 1, kf = (g >> 8) & 1, jt = (g >> 9) & 127, b = g >> 16;
    int jb = jt * 32 + kf * 16 + 4 * hh;
    const float* rp = rls + (size_t)b * W_ + jb;
    float4 r0 = *(const float4*)rp;          // j jb..jb+3  (slots 0-3)
    float4 r1 = *(const float4*)(rp + 8);    // j jb+8..+11 (slots 4-7)
    uint4 v = *(const uint4*)(vws2 + (size_t)g * 8);
    unsigned int o0 = pk2bf(bf2f((unsigned short)(v.x & 0xffffu)) * r0.x,
                            bf2f((unsigned short)(v.x >> 16))     * r0.y);
    unsigned int o1 = pk2bf(bf2f((unsigned short)(v.y & 0xffffu)) * r0.z,
                            bf2f((unsigned short)(v.y >> 16))     * r0.w);
    unsigned int o2 = pk2bf(bf2f((unsigned short)(v.z & 0xffffu)) * r1.x,
                            bf2f((unsigned short)(v.z >> 16))     * r1.y);
    unsigned int o3 = pk2bf(bf2f((unsigned short)(v.w & 0xffffu)) * r1.z,
                            bf2f((unsigned short)(v.w >> 16))     * r1.w);
    *(uint4*)(vws2 + (size_t)g * 8) = make_uint4(o0, o1, o2, o3);
}

// ---------------- attn_out: 8-wave LDS-shared-P pipeline ----------------
// Block: 512 thr, tile 128c x 64w, j-step 128 per iter (32 iters).
// Wave (cq=wid>>1, kh=wid&1):
//   S phase: one 32x32 S subtile (j-tile it*4+cq, w-half kh) -> exp2 -> packed
//            uint4 per lane written to LDS p-tile at identity lane position
//            (reader's ds_read_b128 recovers the proven in-lane B-frag layout).
//   PV phase: c-quarter cq, K-half kh (4 of 8 kf chunks): acc[2] f32x16 only.
// NOTE: q j-tile stride is 512 SHORTS (= 64 uint4) — keep short addressing.
__global__ __launch_bounds__(512, 4) void attn_out(
    const float* __restrict__ x, const unsigned short* __restrict__ qws2,
    const unsigned short* __restrict__ kws2, const unsigned short* __restrict__ vws2,
    float* __restrict__ out)
{
    // p_lds slot: kf_g*128 + h*64 + wh*32 + wl  (uint4 units), kf_g = 16-j chunk 0..7
    __shared__ uint4 p_lds[2][1024];     // 32 KB, double-buffered P
    __shared__ float red[128 * 68];      // 34.8 KB, pair-reduce + store bounce

    int b  = blockIdx.x & 7;
    int w0 = (blockIdx.x >> 3) * 64;
    int tid = threadIdx.x;
    int wid = tid >> 6, lane = tid & 63, wl = lane & 31, h = lane >> 5;
    int cq = wid >> 1, kh = wid & 1;

    const unsigned short* qb  = qws2 + (size_t)b * 65536;
    const unsigned short* kb  = kws2 + (size_t)b * 65536;
    const uint4* vtb4 = (const uint4*)(vws2 + (size_t)b * 524288) + h * 128 + (cq * 32 + wl);
    const int qoff = h * 256 + wl * 8;   // short units within a j-tile

    // loop-invariant k fragment (B of S) for this wave's w-half
    bf16x8 bk = *(const bf16x8*)(kb + (size_t)((w0 >> 5) + kh) * 512 + h * 256 + wl * 8);

    f32x16 zero16 = {0.f,0.f,0.f,0.f,0.f,0.f,0.f,0.f,0.f,0.f,0.f,0.f,0.f,0.f,0.f,0.f};
    f32x16 acc[2];
    acc[0] = zero16; acc[1] = zero16;

    const int wbase = cq * 256 + h * 64 + kh * 32 + wl;   // write slot (kfl=0); +128 kfl=1
    const int rbase = kh * 512 + h * 64 + wl;             // read base; +kf*128 +nt*32

    // ---- prologue: S(0) -> p[0]; vf(0); aq(1) ----
    bf16x8 aq = *(const bf16x8*)(qb + (size_t)cq * 512 + qoff);
    uint4 vf[4];
#pragma unroll
    for (int kf = 0; kf < 4; kf++)
        vf[kf] = vtb4[(size_t)(kh * 4 + kf) * 256];
    {
        f32x16 s = __builtin_amdgcn_mfma_f32_32x32x16_bf16(aq, bk, zero16, 0, 0, 0);
        aq = *(const bf16x8*)(qb + (size_t)(4 + cq) * 512 + qoff);
        p_lds[0][wbase]       = exp2pkq(s, 0);
        p_lds[0][wbase + 128] = exp2pkq(s, 8);
    }
    __syncthreads();

#pragma unroll 2
    for (int it = 0; it < 32; it++) {
        int cur = it & 1, nxt = cur ^ 1;
        // (a) v-frag prefetch for it+1 (4 x dwordx4)
        uint4 vfn[4];
#pragma unroll
        for (int kf = 0; kf < 4; kf++) {
            int kg = ((it + 1) & 31) * 8 + kh * 4 + kf;
            vfn[kf] = vtb4[(size_t)kg * 256];
        }
        // (b) S(it+1) for this wave's subtile
        f32x16 s = __builtin_amdgcn_mfma_f32_32x32x16_bf16(aq, bk, zero16, 0, 0, 0);
        // (c) q frag for it+2
        aq = *(const bf16x8*)(qb + (size_t)(((it + 2) & 31) * 4 + cq) * 512 + qoff);
        // (d) exp2/pack -> p[nxt]
        p_lds[nxt][wbase]       = exp2pkq(s, 0);
        p_lds[nxt][wbase + 128] = exp2pkq(s, 8);
        // (e) PV for it from p[cur] + vf
        __builtin_amdgcn_s_setprio(1);
#pragma unroll
        for (int kf = 0; kf < 4; kf++) {
            bf16x8 af = uint4_as_bf8(vf[kf]);
#pragma unroll
            for (int nt = 0; nt < 2; nt++) {
                bf16x8 bp = uint4_as_bf8(p_lds[cur][rbase + kf * 128 + nt * 32]);
                acc[nt] = __builtin_amdgcn_mfma_f32_32x32x16_bf16(af, bp, acc[nt], 0, 0, 0);
            }
        }
        __builtin_amdgcn_s_setprio(0);
        // (f) barrier: p[nxt] visible for it+1; p[cur] safe to overwrite at it+1
        __syncthreads();
#pragma unroll
        for (int kf = 0; kf < 4; kf++) vf[kf] = vfn[kf];
    }

    // ---- epilogue: sum K-half pairs, then coalesced store ----
    // acc C layout: row c = cq*32 + (r&3)+8*(r>>2)+4h, col w = nt*32 + wl
#define CROW(r) (cq * 32 + ((r) & 3) + 8 * ((r) >> 2) + 4 * h)
    if (kh == 1) {
#pragma unroll
        for (int nt = 0; nt < 2; nt++)
#pragma unroll
            for (int r = 0; r < 16; r++)
                red[CROW(r) * 68 + nt * 32 + wl] = acc[nt][r];
    }
    __syncthreads();
    if (kh == 0) {
#pragma unroll
        for (int nt = 0; nt < 2; nt++)
#pragma unroll
            for (int r = 0; r < 16; r++) {
                int o = CROW(r) * 68 + nt * 32 + wl;
                red[o] += acc[nt][r];
            }
    }
#undef CROW
    __syncthreads();

    // coalesced store: out = red + x   (2048 float4 slots / 512 thr)
#pragma unroll
    for (int u = 0; u < 4; u++) {
        int k = tid + 512 * u;
        int c = k >> 4, wseg = (k & 15) * 4;
        size_t gidx = (size_t)(b * C_ + c) * W_ + w0 + wseg;
        float4 xv = *(const float4*)(x + gidx);
        const float* sp = &red[c * 68 + wseg];
        *(float4*)(out + gidx) = make_float4(sp[0] + xv.x, sp[1] + xv.y, sp[2] + xv.z, sp[3] + xv.w);
    }
}

extern "C" void kernel_launch(void* const* d_in, const int* in_sizes, int n_in,
                              void* d_out, int out_size, void* d_ws, size_t ws_size,
                              hipStream_t stream)
{
    const float* x  = (const float*)d_in[0];
    const float* Wq = (const float*)d_in[1];
    const float* bq = (const float*)d_in[2];
    const float* Wk = (const float*)d_in[3];
    const float* bk = (const float*)d_in[4];
    const float* Wv = (const float*)d_in[5];
    const float* bv = (const float*)d_in[6];
    float* out = (float*)d_out;

    unsigned short* qws2 = (unsigned short*)d_ws;        // [B][128][2][32][8] = 1MB
    unsigned short* kws2 = qws2 + (size_t)524288;        // 1MB
    unsigned short* vws2 = kws2 + (size_t)524288;        // [B][128][2][2][128][8] = 8.4MB
    unsigned short* Wvbf = vws2 + (size_t)4194304;       // [128][128]
    unsigned short* Wqkbf = Wvbf + 16384;                // [32][128]
    float* rlp = (float*)(Wqkbf + 4096);                 // [4][B][W] partial l-sums
    float* rls = rlp + 131072;                           // [B][W] reciprocal l

    prep<<<20, 256, 0, stream>>>(Wq, Wk, Wv, Wvbf, Wqkbf);
    proj<<<1024, 256, 0, stream>>>(x, Wvbf, Wqkbf, bq, bk, bv, qws2, kws2, vws2);
    row_stats<<<1024, 256, 0, stream>>>(qws2, kws2, rlp);
    finl<<<128, 256, 0, stream>>>(rlp, rls);
    vscale<<<2048, 256, 0, stream>>>(vws2, rls);
    attn_out<<<512, 512, 0, stream>>>(x, qws2, kws2, vws2, out);
}